// Round 5
// baseline (689.578 us; speedup 1.0000x reference)
//
#include <hip/hip_runtime.h>
#include <cstdint>
#include <cstddef>

typedef unsigned short ushort_t;
typedef __attribute__((ext_vector_type(8))) short short8;    // 8 bf16 (4 VGPRs)
typedef __attribute__((ext_vector_type(4))) float floatx4;

#define B_   32
#define T_   2048
#define H_   1024
#define U_   1024
#define KN_  32
#define KEXT 1056            // H + KN, = 33 * 32  (Bm row length)
#define BT_  (B_ * T_)       // 65536

// ---------- helpers ----------
__device__ __forceinline__ unsigned int f2bf_u(float f) {
    union { float f; unsigned int u; } v; v.f = f;
    unsigned int u = v.u;
    return (u + 0x7FFFu + ((u >> 16) & 1u)) >> 16;  // RNE
}
__device__ __forceinline__ void async_cp16(const void* g, void* l) {
    __builtin_amdgcn_global_load_lds(
        (const __attribute__((address_space(1))) unsigned int*)g,
        (__attribute__((address_space(3))) unsigned int*)l, 16, 0, 0);
}
__device__ __forceinline__ float fast_tanh(float x) {
    float e = __expf(2.0f * x);
    return 1.0f - 2.0f * __builtin_amdgcn_rcpf(e + 1.0f);
}

#define WAITV(n) asm volatile("s_waitcnt vmcnt(" #n ")" ::: "memory")
#define BARX() do { asm volatile("" ::: "memory"); __builtin_amdgcn_s_barrier(); asm volatile("" ::: "memory"); } while (0)

// ---------- conv(prev_att, conv_w) -> Loc[b*T+t][k] bf16 (loc transposed to (b,t,k)) ----------
__global__ void conv_pack(const float* __restrict__ prev, const float* __restrict__ convw,
                          ushort_t* __restrict__ Loc) {
    __shared__ float satt[158];       // 128 + 2*15
    __shared__ float sw[KN_ * 31];
    const int tid = threadIdx.x;
    const int b = blockIdx.y, t0 = blockIdx.x * 128;
    for (int i = tid; i < 158; i += 256) {
        int t = t0 - 15 + i;
        satt[i] = (t >= 0 && t < T_) ? prev[b * T_ + t] : 0.0f;
    }
    for (int i = tid; i < KN_ * 31; i += 256) sw[i] = convw[i];
    __syncthreads();
    for (int idx = tid; idx < 128 * KN_; idx += 256) {
        const int k = idx & 31, tl = idx >> 5;
        float acc = 0.0f;
#pragma unroll
        for (int j = 0; j < 31; ++j) acc += satt[tl + j] * sw[k * 31 + j];
        Loc[(size_t)(b * T_ + t0 + tl) * KN_ + k] = (ushort_t)f2bf_u(acc);
    }
}

// per u: pack [W1_w | loc_proj] row to Bm bf16 AND bias[b][u] for all 32 b
__global__ void pack_w_bias(const float* __restrict__ W1w, const float* __restrict__ locp,
                            const float* __restrict__ W2w, const float* __restrict__ q,
                            const float* __restrict__ W1b, const float* __restrict__ W2b,
                            ushort_t* __restrict__ Bm, float* __restrict__ bias) {
    const int u = blockIdx.x, tid = threadIdx.x;
    {
        float4 v = reinterpret_cast<const float4*>(W1w + (size_t)u * H_)[tid];
        ushort4 o;
        o.x = (ushort_t)f2bf_u(v.x); o.y = (ushort_t)f2bf_u(v.y);
        o.z = (ushort_t)f2bf_u(v.z); o.w = (ushort_t)f2bf_u(v.w);
        *reinterpret_cast<ushort4*>(Bm + (size_t)u * KEXT + tid * 4) = o;
    }
    if (tid < 8) {
        float4 w = reinterpret_cast<const float4*>(locp + u * KN_)[tid];
        ushort4 o2;
        o2.x = (ushort_t)f2bf_u(w.x); o2.y = (ushort_t)f2bf_u(w.y);
        o2.z = (ushort_t)f2bf_u(w.z); o2.w = (ushort_t)f2bf_u(w.w);
        *reinterpret_cast<ushort4*>(Bm + (size_t)u * KEXT + H_ + tid * 4) = o2;
    }
    const int lane = tid & 63, wave = tid >> 6;
    const float* wr = W2w + (size_t)u * H_;
    float wv[16];
#pragma unroll
    for (int i = 0; i < 16; ++i) wv[i] = wr[lane + i * 64];
    const float bb = W1b[u] + W2b[u];
#pragma unroll
    for (int j = 0; j < 8; ++j) {
        const int b = wave * 8 + j;
        const float* qr = q + b * H_;
        float acc = 0.0f;
#pragma unroll
        for (int i = 0; i < 16; ++i) acc += wv[i] * qr[lane + i * 64];
#pragma unroll
        for (int off = 32; off >= 1; off >>= 1) acc += __shfl_xor(acc, off, 64);
        if (lane == 0) bias[b * U_ + u] = acc + bb;
    }
}

// ---------- fused score GEMM: 256x256 tile, BK=32, 8 waves, fused f32->bf16 A staging ----------
// pack_values is GONE: A is staged from `values` f32 via reg-staging
// (global_load_dwordx4 x4 -> f2bf RNE cvt -> 2x ds_write_b128), producing a
// byte-identical LDS image to the old pre-packed A path.  T14 split: A-loads
// issue before the MFMA cluster, cvt+ds_write after vmcnt(0) post-MFMA, so
// the drain hides under ~2400 cyc of reads+MFMA.  B stays on global_load_lds
// (pre-swizzled source, linear dest).  K tail (k=1024..1055) comes from Loc
// (conv output) + Bm tail via global_load_lds.
// Bank swizzle everywhere: chunk c of row at phys = c ^ ((row>>1)&3), applied
// identically on write and read -> conflict-free (verified R2: conflicts = 0).
__global__ __launch_bounds__(512, 2)
void score_gemm(const float* __restrict__ values, const ushort_t* __restrict__ Loc,
                const ushort_t* __restrict__ Bm, const float* __restrict__ bias,
                const float* __restrict__ Vw, float* __restrict__ sacc) {
    __shared__ __align__(16) ushort_t smA[2][8192];   // 2 bufs x 256 rows x 32 k bf16 = 32 KiB
    __shared__ __align__(16) ushort_t smB[2][8192];   // 32 KiB
    const int tid  = threadIdx.x;
    const int wave = tid >> 6;
    const int lane = tid & 63;
    const int lr   = lane & 15;
    const int quad = lane >> 4;
    const int wr64 = (wave >> 2) * 64;   // wave m-offset within each 128-half
    const int wc32 = (wave & 3) * 32;    // wave n-offset within each 128-half

    // XCD-aware swizzle; 4 n-siblings of one m-panel are consecutive -> same XCD L2
    const int hid = blockIdx.x;                     // 0..1023
    const int lin = (hid & 7) * 128 + (hid >> 3);   // bijective (1024 % 8 == 0)
    const int m0 = (lin >> 2) * 256;                // 256 m-tiles
    const int n0 = (lin & 3) * 256;                 // 4 n-tiles

    const ushort_t* Bblk = Bm + (size_t)n0 * KEXT;
    const ushort_t* Lblk = Loc + (size_t)m0 * KN_;

    // ---- A staging (f32 source): thread handles row = tid>>1, k-half = (tid&1)*16
    const int arow = tid >> 1;
    const int ah   = tid & 1;
    const float* gAbase = values + (size_t)(m0 + arow) * H_ + ah * 16;
    const int ax  = (arow >> 1) & 3;                 // row swizzle key
    const int pw0 = ((2 * ah)     ^ ax) * 8;         // phys chunk byte/2 offsets
    const int pw1 = ((2 * ah + 1) ^ ax) * 8;
    const int awbase = arow * 32;                    // ushort offset of row

    // ---- B / tail staging source offsets (gload_lds, inverse-swizzled source)
    int off[2], locOff[2];
#pragma unroll
    for (int j = 0; j < 2; ++j) {
        const int s = j * 512 + tid;
        const int row = s >> 2;
        const int c = (s & 3) ^ ((row >> 1) & 3);
        off[j]    = row * KEXT + c * 8;
        locOff[j] = row * KN_  + c * 8;
    }

    // ---- per-lane LDS read offsets (loop-invariant)
    int aoff[8], boff[4];
#pragma unroll
    for (int mi = 0; mi < 8; ++mi) {
        const int row = (mi >> 2) * 128 + wr64 + (mi & 3) * 16 + lr;
        aoff[mi] = row * 32 + (quad ^ ((row >> 1) & 3)) * 8;
    }
#pragma unroll
    for (int ni = 0; ni < 4; ++ni) {
        const int row = (ni >> 1) * 128 + wc32 + (ni & 1) * 16 + lr;
        boff[ni] = row * 32 + (quad ^ ((row >> 1) & 3)) * 8;
    }

    floatx4 acc[8][4] = {};
    short8 aF[8], bF[4];

    // ---- prologue: stage tile 0
    {
        float4 f0 = *reinterpret_cast<const float4*>(gAbase);
        float4 f1 = *reinterpret_cast<const float4*>(gAbase + 4);
        float4 f2 = *reinterpret_cast<const float4*>(gAbase + 8);
        float4 f3 = *reinterpret_cast<const float4*>(gAbase + 12);
        async_cp16(Bblk + off[0], &smB[0][wave * 512]);
        async_cp16(Bblk + off[1], &smB[0][4096 + wave * 512]);
        WAITV(0);
        uint4 q0, q1;
        q0.x = f2bf_u(f0.x) | (f2bf_u(f0.y) << 16);
        q0.y = f2bf_u(f0.z) | (f2bf_u(f0.w) << 16);
        q0.z = f2bf_u(f1.x) | (f2bf_u(f1.y) << 16);
        q0.w = f2bf_u(f1.z) | (f2bf_u(f1.w) << 16);
        q1.x = f2bf_u(f2.x) | (f2bf_u(f2.y) << 16);
        q1.y = f2bf_u(f2.z) | (f2bf_u(f2.w) << 16);
        q1.z = f2bf_u(f3.x) | (f2bf_u(f3.y) << 16);
        q1.w = f2bf_u(f3.z) | (f2bf_u(f3.w) << 16);
        *reinterpret_cast<uint4*>(&smA[0][awbase + pw0]) = q0;
        *reinterpret_cast<uint4*>(&smA[0][awbase + pw1]) = q1;
        BARX();
    }

#pragma unroll 1
    for (int t = 0; t < 33; ++t) {
        const ushort_t* sA = &smA[t & 1][0];
        const ushort_t* sB = &smB[t & 1][0];
        const int tn = t + 1;

        // ---- issue next-tile stages (A f32 -> regs; B via gload_lds)
        float4 f0, f1, f2, f3;
        if (tn <= 31) {
            const float* g = gAbase + tn * 32;
            f0 = *reinterpret_cast<const float4*>(g);
            f1 = *reinterpret_cast<const float4*>(g + 4);
            f2 = *reinterpret_cast<const float4*>(g + 8);
            f3 = *reinterpret_cast<const float4*>(g + 12);
            async_cp16(Bblk + tn * 32 + off[0], &smB[tn & 1][wave * 512]);
            async_cp16(Bblk + tn * 32 + off[1], &smB[tn & 1][4096 + wave * 512]);
        } else if (tn == 32) {   // K tail: A from Loc, B from Bm cols 1024..1055
            async_cp16(Lblk + locOff[0], &smA[0][wave * 512]);
            async_cp16(Lblk + locOff[1], &smA[0][4096 + wave * 512]);
            async_cp16(Bblk + 1024 + off[0], &smB[0][wave * 512]);
            async_cp16(Bblk + 1024 + off[1], &smB[0][4096 + wave * 512]);
        }

        // ---- 12 ds_read_b128 (tile t); aF[0]+bF first for early MFMA deps
        aF[0] = *reinterpret_cast<const short8*>(sA + aoff[0]);
#pragma unroll
        for (int ni = 0; ni < 4; ++ni)
            bF[ni] = *reinterpret_cast<const short8*>(sB + boff[ni]);
#pragma unroll
        for (int mi = 1; mi < 8; ++mi)
            aF[mi] = *reinterpret_cast<const short8*>(sA + aoff[mi]);

        __builtin_amdgcn_s_setprio(1);
#pragma unroll
        for (int mi = 0; mi < 8; ++mi)
#pragma unroll
            for (int ni = 0; ni < 4; ++ni)
                acc[mi][ni] = __builtin_amdgcn_mfma_f32_16x16x32_bf16(aF[mi], bF[ni], acc[mi][ni], 0, 0, 0);
        __builtin_amdgcn_s_setprio(0);

        // ---- land stages, write A bf16, publish
        if (tn <= 31) {
            WAITV(0);        // f-regs + B(tn) landed (issued ~2400 cyc ago)
            uint4 q0, q1;
            q0.x = f2bf_u(f0.x) | (f2bf_u(f0.y) << 16);
            q0.y = f2bf_u(f0.z) | (f2bf_u(f0.w) << 16);
            q0.z = f2bf_u(f1.x) | (f2bf_u(f1.y) << 16);
            q0.w = f2bf_u(f1.z) | (f2bf_u(f1.w) << 16);
            q1.x = f2bf_u(f2.x) | (f2bf_u(f2.y) << 16);
            q1.y = f2bf_u(f2.z) | (f2bf_u(f2.w) << 16);
            q1.z = f2bf_u(f3.x) | (f2bf_u(f3.y) << 16);
            q1.w = f2bf_u(f3.z) | (f2bf_u(f3.w) << 16);
            ushort_t* wp = &smA[tn & 1][awbase];
            *reinterpret_cast<uint4*>(wp + pw0) = q0;
            *reinterpret_cast<uint4*>(wp + pw1) = q1;
            BARX();          // all waves' writes/stages visible before reads(t+1)
        } else if (tn == 32) {
            WAITV(0);
            BARX();
        }
        // tn == 33 (t == 32): last tile, nothing to publish
    }

    // epilogue: sum_1 -> tanh -> *Vw -> reduce over this wave's 64 u-cols -> atomic partial
    const int bb = m0 >> 11;
    float vw[4], bv[4];
#pragma unroll
    for (int ni = 0; ni < 4; ++ni) {
        const int u = n0 + (ni >> 1) * 128 + wc32 + (ni & 1) * 16 + lr;
        vw[ni] = Vw[u];
        bv[ni] = bias[bb * U_ + u];
    }
#pragma unroll
    for (int mi = 0; mi < 8; ++mi) {
        const int mrow = m0 + (mi >> 2) * 128 + wr64 + (mi & 3) * 16 + quad * 4;
#pragma unroll
        for (int r = 0; r < 4; ++r) {
            float s = 0.0f;
#pragma unroll
            for (int ni = 0; ni < 4; ++ni)
                s += vw[ni] * fast_tanh(acc[mi][ni][r] + bv[ni]);
            s += __shfl_xor(s, 1, 64);
            s += __shfl_xor(s, 2, 64);
            s += __shfl_xor(s, 4, 64);
            s += __shfl_xor(s, 8, 64);
            if (lr == 0)
                atomicAdd(&sacc[mrow + r], s);
        }
    }
}

// ---------- softmax over T per b; writes score and attn outputs ----------
__global__ void softmax_k(const float* __restrict__ sacc, const float* __restrict__ Vb,
                          float* __restrict__ out) {
    const int b = blockIdx.x, tid = threadIdx.x;
    const int lane = tid & 63, wave = tid >> 6;
    const float vb = Vb[0];
    float v[8], e[8];
    float mx = -1e30f;
#pragma unroll
    for (int j = 0; j < 8; ++j) {
        v[j] = sacc[b * T_ + j * 256 + tid] + vb;
        out[98304 + b * T_ + j * 256 + tid] = v[j];   // score output
        mx = fmaxf(mx, v[j]);
    }
#pragma unroll
    for (int off = 32; off >= 1; off >>= 1) mx = fmaxf(mx, __shfl_xor(mx, off, 64));
    __shared__ float sm[4], ss[4];
    if (lane == 0) sm[wave] = mx;
    __syncthreads();
    mx = fmaxf(fmaxf(sm[0], sm[1]), fmaxf(sm[2], sm[3]));
    float sum = 0.0f;
#pragma unroll
    for (int j = 0; j < 8; ++j) { e[j] = __expf(v[j] - mx); sum += e[j]; }
#pragma unroll
    for (int off = 32; off >= 1; off >>= 1) sum += __shfl_xor(sum, off, 64);
    if (lane == 0) ss[wave] = sum;
    __syncthreads();
    sum = ss[0] + ss[1] + ss[2] + ss[3];
    const float inv = 1.0f / sum;
#pragma unroll
    for (int j = 0; j < 8; ++j)
        out[32768 + b * T_ + j * 256 + tid] = e[j] * inv;  // attention output
}

// ---------- context = sum_t attn[b,t] * values[b,t,h] (direct f32 read) ----------
__global__ void context_k(const float* __restrict__ values, const float* __restrict__ attn,
                          float* __restrict__ ctx) {
    const int b = blockIdx.y, tc = blockIdx.x, tid = threadIdx.x;
    __shared__ float sa[128];
    if (tid < 128) sa[tid] = attn[b * T_ + tc * 128 + tid];
    __syncthreads();
    const int hh = (tid & 127) * 8;   // 8 h-elements per thread
    const int tp = tid >> 7;          // row-pair 0/1
    const float* base = values + (size_t)(b * T_ + tc * 128 + tp) * H_ + hh;
    float a[8] = {0, 0, 0, 0, 0, 0, 0, 0};
    for (int t = 0; t < 128; t += 2) {
        const float w = sa[t + tp];
        float4 u0 = *reinterpret_cast<const float4*>(base + (size_t)t * H_);
        float4 u1 = *reinterpret_cast<const float4*>(base + (size_t)t * H_ + 4);
        a[0] += w * u0.x; a[1] += w * u0.y;
        a[2] += w * u0.z; a[3] += w * u0.w;
        a[4] += w * u1.x; a[5] += w * u1.y;
        a[6] += w * u1.z; a[7] += w * u1.w;
    }
#pragma unroll
    for (int j = 0; j < 8; ++j)
        atomicAdd(&ctx[b * H_ + hh + j], a[j]);
}

// ---------- launch ----------
extern "C" void kernel_launch(void* const* d_in, const int* in_sizes, int n_in,
                              void* d_out, int out_size, void* d_ws, size_t ws_size,
                              hipStream_t stream) {
    const float* query    = (const float*)d_in[0];
    const float* values   = (const float*)d_in[1];
    const float* prev_att = (const float*)d_in[2];
    const float* W1w      = (const float*)d_in[3];
    const float* W1b      = (const float*)d_in[4];
    const float* W2w      = (const float*)d_in[5];
    const float* W2b      = (const float*)d_in[6];
    const float* Vw       = (const float*)d_in[7];
    const float* Vb       = (const float*)d_in[8];
    const float* convw    = (const float*)d_in[9];
    const float* locp     = (const float*)d_in[10];
    float* out = (float*)d_out;

    char* ws = (char*)d_ws;
    ushort_t* Loc  = (ushort_t*)(ws);                  // 65536*32*2   = 4,194,304 B
    ushort_t* Bm   = (ushort_t*)(ws + 4194304);        // 1024*1056*2  = 2,162,688 B
    float*    bias = (float*)(ws + 6356992);           // 32*1024*4    =   131,072 B
    float*    sacc = (float*)(ws + 6488064);           // 65536*4      =   262,144 B

    hipMemsetAsync(sacc, 0, BT_ * sizeof(float), stream);
    hipMemsetAsync(out, 0, 32768 * sizeof(float), stream);   // context via atomics

    conv_pack<<<dim3(16, 32), 256, 0, stream>>>(prev_att, convw, Loc);
    pack_w_bias<<<1024, 256, 0, stream>>>(W1w, locp, W2w, query, W1b, W2b, Bm, bias);
    score_gemm<<<1024, 512, 0, stream>>>(values, Loc, Bm, bias, Vw, sacc);
    softmax_k<<<32, 256, 0, stream>>>(sacc, Vb, out);
    context_k<<<dim3(16, 32), 256, 0, stream>>>(values, out + 32768, out);
}